// Round 7
// baseline (337.679 us; speedup 1.0000x reference)
//
#include <hip/hip_runtime.h>
#include <math.h>

// GAT 2-layer, N=100K nodes, E=1.6M edges (+N self loops), fp32 compute,
// bf16 feature rows for the edge gather.
// CSR build via 2-level bucket sort (bucket = dst>>7, 128 nodes/bucket).
// agg: LDS-free. Per 64-edge chunk: lane-strided csr load -> shfl src to
// groups -> h-gathers issue early (exp overlaps load latency) -> shfl w ->
// FMA. Branch-free 32-edge unrolled blocks, padded with (src=i, w=0).

constexpr int F_IN = 128;
constexpr int F_H  = 64;
constexpr int F_O  = 40;
constexpr int BSH  = 7;                  // bucket shift
constexpr int BNODES = 1 << BSH;         // 128 nodes per bucket
constexpr int NBMAX = 1024;              // max buckets (N <= 131072)
constexpr int CHUNK = 8192;              // edges per block in k_binC

__device__ __forceinline__ unsigned f2bf(float f) {    // RNE float->bf16 bits
    unsigned u = __float_as_uint(f);
    return (u + 0x7FFFu + ((u >> 16) & 1u)) >> 16;
}
__device__ __forceinline__ float bflo(unsigned u) { return __uint_as_float(u << 16); }
__device__ __forceinline__ float bfhi(unsigned u) { return __uint_as_float(u & 0xFFFF0000u); }

// ---------------- CSR build: bucket sort ----------------

__global__ __launch_bounds__(256) void k_binA(const int* __restrict__ dsts,
                                              int* __restrict__ bcnt,
                                              int E, int Et, int NB) {
    __shared__ int hist[NBMAX];
    for (int i = threadIdx.x; i < NB; i += 256) hist[i] = 0;
    __syncthreads();
    int e0 = blockIdx.x * 2048;
#pragma unroll
    for (int it = 0; it < 8; ++it) {
        int e = e0 + it * 256 + threadIdx.x;
        if (e < Et) {
            int d = (e < E) ? dsts[e] : (e - E);
            atomicAdd(&hist[d >> BSH], 1);
        }
    }
    __syncthreads();
    for (int i = threadIdx.x; i < NB; i += 256) {
        int c = hist[i];
        if (c) atomicAdd(&bcnt[i], c);
    }
}

// Scan up to 1024 bucket counts with one 256-thread block (4/thread).
__global__ __launch_bounds__(256) void k_binB(const int* __restrict__ bcnt,
                                              int* __restrict__ bbase,
                                              int* __restrict__ bcur,
                                              int* __restrict__ rp,
                                              int NB, int N, int Et) {
    __shared__ int lds[256];
    int t = threadIdx.x;
    int b4 = t * 4;
    int v0 = (b4 + 0 < NB) ? bcnt[b4 + 0] : 0;
    int v1 = (b4 + 1 < NB) ? bcnt[b4 + 1] : 0;
    int v2 = (b4 + 2 < NB) ? bcnt[b4 + 2] : 0;
    int v3 = (b4 + 3 < NB) ? bcnt[b4 + 3] : 0;
    int tot = v0 + v1 + v2 + v3;
    lds[t] = tot; __syncthreads();
    int x = tot;
    for (int o = 1; o < 256; o <<= 1) {
        int y = (t >= o) ? lds[t - o] : 0;
        __syncthreads();
        x += y;
        lds[t] = x;
        __syncthreads();
    }
    int ex = x - tot;
    if (b4 + 0 < NB) { bbase[b4 + 0] = ex; bcur[b4 + 0] = ex; } ex += v0;
    if (b4 + 1 < NB) { bbase[b4 + 1] = ex; bcur[b4 + 1] = ex; } ex += v1;
    if (b4 + 2 < NB) { bbase[b4 + 2] = ex; bcur[b4 + 2] = ex; } ex += v2;
    if (b4 + 3 < NB) { bbase[b4 + 3] = ex; bcur[b4 + 3] = ex; }
    if (t == 0) rp[N] = Et;
}

__global__ __launch_bounds__(256) void k_binC(const int* __restrict__ srcs,
                                              const int* __restrict__ dsts,
                                              int* __restrict__ bcur,
                                              unsigned* __restrict__ binned,
                                              int E, int Et, int NB) {
    __shared__ int hist[NBMAX];
    __shared__ int gbase[NBMAX];
    __shared__ int lcnt[NBMAX];
    int t = threadIdx.x;
    for (int i = t; i < NB; i += 256) hist[i] = 0;
    __syncthreads();
    int e0 = blockIdx.x * CHUNK;
#pragma unroll 4
    for (int it = 0; it < CHUNK / 256; ++it) {
        int e = e0 + it * 256 + t;
        if (e < Et) {
            int d = (e < E) ? dsts[e] : (e - E);
            atomicAdd(&hist[d >> BSH], 1);
        }
    }
    __syncthreads();
    for (int i = t; i < NB; i += 256) {
        int c = hist[i];
        gbase[i] = c ? atomicAdd(&bcur[i], c) : 0;
        lcnt[i] = 0;
    }
    __syncthreads();
#pragma unroll 4
    for (int it = 0; it < CHUNK / 256; ++it) {
        int e = e0 + it * 256 + t;
        if (e < Et) {
            int s, d;
            if (e < E) { s = srcs[e]; d = dsts[e]; } else { s = e - E; d = s; }
            int b = d >> BSH;
            int p = atomicAdd(&lcnt[b], 1);
            binned[gbase[b] + p] = (unsigned)s | ((unsigned)(d & (BNODES - 1)) << 24);
        }
    }
}

__global__ __launch_bounds__(256) void k_binD(const unsigned* __restrict__ binned,
                                              const int* __restrict__ bbase,
                                              const int* __restrict__ bcur,
                                              int* __restrict__ rp,
                                              int* __restrict__ csr, int N) {
    __shared__ int hist[BNODES];
    __shared__ int sc[256];
    __shared__ int lcnt[BNODES];
    int b = blockIdx.x, t = threadIdx.x;
    int base = bbase[b], end = bcur[b];
    if (t < BNODES) hist[t] = 0;
    __syncthreads();
    for (int j = base + t; j < end; j += 256)
        atomicAdd(&hist[binned[j] >> 24], 1);
    __syncthreads();
    int v = (t < BNODES) ? hist[t] : 0;
    sc[t] = v; __syncthreads();
    int x = v;
    for (int o = 1; o < BNODES; o <<= 1) {
        int y = (t >= o) ? sc[t - o] : 0;
        __syncthreads();
        x += y;
        sc[t] = x;
        __syncthreads();
    }
    int pref = x - v;
    int g = (b << BSH) + t;
    if (t < BNODES && g < N) rp[g] = base + pref;
    if (t < BNODES) { sc[t] = pref; lcnt[t] = 0; }
    __syncthreads();
    for (int j = base + t; j < end; j += 256) {
        unsigned w = binned[j];
        int v2 = (int)(w >> 24);
        int s = (int)(w & 0xFFFFFFu);
        int p = atomicAdd(&lcnt[v2], 1);
        csr[base + sc[v2] + p] = s;
    }
}

// ---------------- GEMM1: h1 = bf16(x @ W1), fused fp32 alphas ----------------

__global__ __launch_bounds__(256) void k_gemm1(const float* __restrict__ x,
                                               const float* __restrict__ W,
                                               const float* __restrict__ avs,
                                               const float* __restrict__ avd,
                                               unsigned short* __restrict__ h,
                                               float* __restrict__ as,
                                               float* __restrict__ ad, int N) {
    __shared__ __align__(16) float Ws[F_IN * F_H];
    for (int i = threadIdx.x; i < F_IN * F_H; i += 256) Ws[i] = W[i];
    __syncthreads();
    int t = threadIdx.x;
    int r0 = blockIdx.x * 64 + (t >> 4) * 4;
    int c0 = (t & 15) * 4;
    if (r0 >= N) return;
    const float* xp = x + (size_t)r0 * F_IN;
    float acc[4][4] = {};
    for (int k4 = 0; k4 < F_IN / 4; ++k4) {
        int kb = k4 * 4;
        float4 w0 = *(const float4*)&Ws[(kb + 0) * F_H + c0];
        float4 w1 = *(const float4*)&Ws[(kb + 1) * F_H + c0];
        float4 w2 = *(const float4*)&Ws[(kb + 2) * F_H + c0];
        float4 w3 = *(const float4*)&Ws[(kb + 3) * F_H + c0];
#pragma unroll
        for (int r = 0; r < 4; ++r) {
            float4 xv = *(const float4*)&xp[(size_t)r * F_IN + kb];
            acc[r][0] += xv.x * w0.x + xv.y * w1.x + xv.z * w2.x + xv.w * w3.x;
            acc[r][1] += xv.x * w0.y + xv.y * w1.y + xv.z * w2.y + xv.w * w3.y;
            acc[r][2] += xv.x * w0.z + xv.y * w1.z + xv.z * w2.z + xv.w * w3.z;
            acc[r][3] += xv.x * w0.w + xv.y * w1.w + xv.z * w2.w + xv.w * w3.w;
        }
    }
    float4 avs4 = *(const float4*)&avs[c0];
    float4 avd4 = *(const float4*)&avd[c0];
#pragma unroll
    for (int r = 0; r < 4; ++r) {
        unsigned lo = f2bf(acc[r][0]) | (f2bf(acc[r][1]) << 16);
        unsigned hi = f2bf(acc[r][2]) | (f2bf(acc[r][3]) << 16);
        ((uint2*)h)[((size_t)(r0 + r) * F_H + c0) >> 2] = make_uint2(lo, hi);
        float ps = acc[r][0] * avs4.x + acc[r][1] * avs4.y + acc[r][2] * avs4.z + acc[r][3] * avs4.w;
        float pd = acc[r][0] * avd4.x + acc[r][1] * avd4.y + acc[r][2] * avd4.z + acc[r][3] * avd4.w;
#pragma unroll
        for (int o = 8; o; o >>= 1) {
            ps += __shfl_xor(ps, o, 16);
            pd += __shfl_xor(pd, o, 16);
        }
        if ((t & 15) == 0) { as[r0 + r] = ps; ad[r0 + r] = pd; }
    }
}

// ---------------- GEMM2: h2 = bf16(out1 @ W2) padded to 64 cols ----------------

__global__ __launch_bounds__(256) void k_gemm2(const float* __restrict__ xin,
                                               const float* __restrict__ W,
                                               const float* __restrict__ avs,
                                               const float* __restrict__ avd,
                                               unsigned short* __restrict__ h,
                                               float* __restrict__ as,
                                               float* __restrict__ ad, int N) {
    __shared__ __align__(16) float Ws[F_H * F_O];
    for (int i = threadIdx.x; i < F_H * F_O; i += 256) Ws[i] = W[i];
    __syncthreads();
    int t = threadIdx.x;
    int r0 = blockIdx.x * 64 + (t >> 3) * 2;
    int l = t & 7;
    if (r0 >= N) return;
    const float4* xa = (const float4*)(xin + (size_t)r0 * F_H);
    const float4* xb = (const float4*)(xin + (size_t)(r0 + 1) * F_H);
    float acca[5] = {}, accb[5] = {};
#pragma unroll
    for (int k4 = 0; k4 < F_H / 4; ++k4) {
        float4 xva = xa[k4];
        float4 xvb = xb[k4];
        int kb = k4 * 4;
#pragma unroll
        for (int kk = 0; kk < 4; ++kk) {
            const float* wr = &Ws[(kb + kk) * F_O + l];
            float w0 = wr[0], w1 = wr[8], w2 = wr[16], w3 = wr[24], w4 = wr[32];
            float xs = (&xva.x)[kk];
            acca[0] += xs * w0; acca[1] += xs * w1; acca[2] += xs * w2;
            acca[3] += xs * w3; acca[4] += xs * w4;
            float ys = (&xvb.x)[kk];
            accb[0] += ys * w0; accb[1] += ys * w1; accb[2] += ys * w2;
            accb[3] += ys * w3; accb[4] += ys * w4;
        }
    }
    float psa = 0.f, pda = 0.f, psb = 0.f, pdb = 0.f;
    unsigned short* ra = h + (size_t)r0 * F_H;     // padded row stride 64
    unsigned short* rb = h + (size_t)(r0 + 1) * F_H;
#pragma unroll
    for (int cc = 0; cc < 5; ++cc) {
        int c = l + 8 * cc;
        ra[c] = (unsigned short)f2bf(acca[cc]);
        rb[c] = (unsigned short)f2bf(accb[cc]);
        float vs = avs[c], vd = avd[c];
        psa += acca[cc] * vs; pda += acca[cc] * vd;
        psb += accb[cc] * vs; pdb += accb[cc] * vd;
    }
#pragma unroll
    for (int pp = 0; pp < 3; ++pp) {               // zero pad cols 40..63
        int c = 40 + l * 3 + pp;
        ra[c] = 0; rb[c] = 0;
    }
#pragma unroll
    for (int o = 4; o; o >>= 1) {
        psa += __shfl_xor(psa, o, 8);
        pda += __shfl_xor(pda, o, 8);
        psb += __shfl_xor(psb, o, 8);
        pdb += __shfl_xor(pdb, o, 8);
    }
    if (l == 0) { as[r0] = psa; ad[r0] = pda; as[r0 + 1] = psb; ad[r0 + 1] = pdb; }
}

// ---------------- Aggregation: one wave per dst node, LDS-free ----------------
// Per 64-edge chunk: lane-strided csr load; shfl src indices to the 8 groups
// so the h-gathers issue immediately; exp (weights) computed in parallel with
// gather latency, shfl'd at FMA time. Padded lanes: src=i, w=0.

template <int FOUT, bool RELU, bool LOGSM>
__global__ __launch_bounds__(256) void k_agg(const int* __restrict__ rp,
                                             const int* __restrict__ csr,
                                             const float* __restrict__ as,
                                             const float* __restrict__ ad,
                                             const uint4* __restrict__ h4,
                                             const float* __restrict__ bias,
                                             float* __restrict__ out, int N) {
    int lane = threadIdx.x & 63;
    int i = (blockIdx.x * 256 + threadIdx.x) >> 6;
    if (i >= N) return;
    int start = rp[i], end = rp[i + 1];
    float adi = ad[i];
    int grp = lane >> 3, c = lane & 7;
    float acc[8] = {}, acc2[8] = {};
    float sacc = 0.f;

    for (int base = start; base < end; base += 64) {
        int cnt = end - base; if (cnt > 64) cnt = 64;
        int srcn = i;
        if (lane < cnt) srcn = csr[base + lane];
        // broadcast src for first 32 edges; issue gathers ASAP
        int s0 = __shfl(srcn, grp, 64);
        int s1 = __shfl(srcn, 8 + grp, 64);
        int s2 = __shfl(srcn, 16 + grp, 64);
        int s3 = __shfl(srcn, 24 + grp, 64);
        uint4 hv0 = h4[(size_t)s0 * 8 + c];
        uint4 hv1 = h4[(size_t)s1 * 8 + c];
        uint4 hv2 = h4[(size_t)s2 * 8 + c];
        uint4 hv3 = h4[(size_t)s3 * 8 + c];
        // weights overlap the gather latency
        float e = as[srcn] + adi;
        e = (e > 0.f) ? e : 0.2f * e;
        float w = (lane < cnt) ? __expf(e) : 0.f;
        sacc += w;
        float w0 = __shfl(w, grp, 64);
        float w1 = __shfl(w, 8 + grp, 64);
        float w2 = __shfl(w, 16 + grp, 64);
        float w3 = __shfl(w, 24 + grp, 64);
        acc[0] += w0 * bflo(hv0.x); acc[1] += w0 * bfhi(hv0.x);
        acc[2] += w0 * bflo(hv0.y); acc[3] += w0 * bfhi(hv0.y);
        acc[4] += w0 * bflo(hv0.z); acc[5] += w0 * bfhi(hv0.z);
        acc[6] += w0 * bflo(hv0.w); acc[7] += w0 * bfhi(hv0.w);
        acc2[0] += w1 * bflo(hv1.x); acc2[1] += w1 * bfhi(hv1.x);
        acc2[2] += w1 * bflo(hv1.y); acc2[3] += w1 * bfhi(hv1.y);
        acc2[4] += w1 * bflo(hv1.z); acc2[5] += w1 * bfhi(hv1.z);
        acc2[6] += w1 * bflo(hv1.w); acc2[7] += w1 * bfhi(hv1.w);
        acc[0] += w2 * bflo(hv2.x); acc[1] += w2 * bfhi(hv2.x);
        acc[2] += w2 * bflo(hv2.y); acc[3] += w2 * bfhi(hv2.y);
        acc[4] += w2 * bflo(hv2.z); acc[5] += w2 * bfhi(hv2.z);
        acc[6] += w2 * bflo(hv2.w); acc[7] += w2 * bfhi(hv2.w);
        acc2[0] += w3 * bflo(hv3.x); acc2[1] += w3 * bfhi(hv3.x);
        acc2[2] += w3 * bflo(hv3.y); acc2[3] += w3 * bfhi(hv3.y);
        acc2[4] += w3 * bflo(hv3.z); acc2[5] += w3 * bfhi(hv3.z);
        acc2[6] += w3 * bflo(hv3.w); acc2[7] += w3 * bfhi(hv3.w);

        if (cnt > 32) {     // wave-uniform; edges 32..63 of the chunk
            int t0 = __shfl(srcn, 32 + grp, 64);
            int t1 = __shfl(srcn, 40 + grp, 64);
            int t2 = __shfl(srcn, 48 + grp, 64);
            int t3 = __shfl(srcn, 56 + grp, 64);
            uint4 gv0 = h4[(size_t)t0 * 8 + c];
            uint4 gv1 = h4[(size_t)t1 * 8 + c];
            uint4 gv2 = h4[(size_t)t2 * 8 + c];
            uint4 gv3 = h4[(size_t)t3 * 8 + c];
            float u0 = __shfl(w, 32 + grp, 64);
            float u1 = __shfl(w, 40 + grp, 64);
            float u2 = __shfl(w, 48 + grp, 64);
            float u3 = __shfl(w, 56 + grp, 64);
            acc[0] += u0 * bflo(gv0.x); acc[1] += u0 * bfhi(gv0.x);
            acc[2] += u0 * bflo(gv0.y); acc[3] += u0 * bfhi(gv0.y);
            acc[4] += u0 * bflo(gv0.z); acc[5] += u0 * bfhi(gv0.z);
            acc[6] += u0 * bflo(gv0.w); acc[7] += u0 * bfhi(gv0.w);
            acc2[0] += u1 * bflo(gv1.x); acc2[1] += u1 * bfhi(gv1.x);
            acc2[2] += u1 * bflo(gv1.y); acc2[3] += u1 * bfhi(gv1.y);
            acc2[4] += u1 * bflo(gv1.z); acc2[5] += u1 * bfhi(gv1.z);
            acc2[6] += u1 * bflo(gv1.w); acc2[7] += u1 * bfhi(gv1.w);
            acc[0] += u2 * bflo(gv2.x); acc[1] += u2 * bfhi(gv2.x);
            acc[2] += u2 * bflo(gv2.y); acc[3] += u2 * bfhi(gv2.y);
            acc[4] += u2 * bflo(gv2.z); acc[5] += u2 * bfhi(gv2.z);
            acc[6] += u2 * bflo(gv2.w); acc[7] += u2 * bfhi(gv2.w);
            acc2[0] += u3 * bflo(gv3.x); acc2[1] += u3 * bfhi(gv3.x);
            acc2[2] += u3 * bflo(gv3.y); acc2[3] += u3 * bfhi(gv3.y);
            acc2[4] += u3 * bflo(gv3.z); acc2[5] += u3 * bfhi(gv3.z);
            acc2[6] += u3 * bflo(gv3.w); acc2[7] += u3 * bfhi(gv3.w);
        }
    }
#pragma unroll
    for (int k = 0; k < 8; ++k) acc[k] += acc2[k];
#pragma unroll
    for (int o = 8; o <= 32; o <<= 1)
#pragma unroll
        for (int k = 0; k < 8; ++k) acc[k] += __shfl_xor(acc[k], o);
#pragma unroll
    for (int o = 32; o; o >>= 1) sacc += __shfl_xor(sacc, o);
    float inv = 1.f / sacc;

    if (!LOGSM) {
        if (lane < 8) {
            float r[8];
#pragma unroll
            for (int k = 0; k < 8; ++k) {
                r[k] = acc[k] * inv + bias[8 * lane + k];
                if (RELU) r[k] = fmaxf(r[k], 0.f);
            }
            float4* op = (float4*)(out + (size_t)i * FOUT + 8 * lane);
            op[0] = make_float4(r[0], r[1], r[2], r[3]);
            op[1] = make_float4(r[4], r[5], r[6], r[7]);
        }
    } else {
        constexpr int VC = FOUT / 8;         // valid chunks (5 for FOUT=40)
        bool act = (lane < VC);
        float v[8];
#pragma unroll
        for (int k = 0; k < 8; ++k)
            v[k] = act ? (acc[k] * inv + bias[8 * lane + k]) : -INFINITY;
        float mx = v[0];
#pragma unroll
        for (int k = 1; k < 8; ++k) mx = fmaxf(mx, v[k]);
#pragma unroll
        for (int o = 1; o <= 4; o <<= 1) mx = fmaxf(mx, __shfl_xor(mx, o));
        float es = 0.f;
        if (act) {
#pragma unroll
            for (int k = 0; k < 8; ++k) es += __expf(v[k] - mx);
        }
#pragma unroll
        for (int o = 1; o <= 4; o <<= 1) es += __shfl_xor(es, o);
        if (act) {
            float lse = mx + __logf(es);
            float4* op = (float4*)(out + (size_t)i * FOUT + 8 * lane);
            op[0] = make_float4(v[0] - lse, v[1] - lse, v[2] - lse, v[3] - lse);
            op[1] = make_float4(v[4] - lse, v[5] - lse, v[6] - lse, v[7] - lse);
        }
    }
}

// ---------------- launch ----------------

extern "C" void kernel_launch(void* const* d_in, const int* in_sizes, int n_in,
                              void* d_out, int out_size, void* d_ws, size_t ws_size,
                              hipStream_t stream) {
    const float* x   = (const float*)d_in[0];
    const int* edges = (const int*)d_in[1];
    const float* W1  = (const float*)d_in[2];
    const float* av_s1 = (const float*)d_in[3];
    const float* av_d1 = (const float*)d_in[4];
    const float* b1  = (const float*)d_in[5];
    const float* W2  = (const float*)d_in[6];
    const float* av_s2 = (const float*)d_in[7];
    const float* av_d2 = (const float*)d_in[8];
    const float* b2  = (const float*)d_in[9];
    float* out = (float*)d_out;

    const int N  = in_sizes[0] / F_IN;
    const int E  = in_sizes[1] / 2;
    const int Et = E + N;
    const int NB = (N + BNODES - 1) >> BSH;

    char* p = (char*)d_ws;
    auto alloc = [&](size_t bytes) {
        char* q = p;
        p += (bytes + 255) & ~(size_t)255;
        return (void*)q;
    };
    unsigned short* h1 = (unsigned short*)alloc((size_t)N * F_H * 2);  // bf16; reused as h2 (padded to 64)
    float* out1   = (float*)alloc((size_t)N * F_H * 4);
    float* as1    = (float*)alloc((size_t)N * 4);
    float* ad1    = (float*)alloc((size_t)N * 4);
    float* as2    = (float*)alloc((size_t)N * 4);
    float* ad2    = (float*)alloc((size_t)N * 4);
    int* rp       = (int*)alloc((size_t)(N + 1) * 4);
    int* bcnt     = (int*)alloc(NBMAX * 4);
    int* bbase    = (int*)alloc(NBMAX * 4);
    int* bcur     = (int*)alloc(NBMAX * 4);
    unsigned* binned = (unsigned*)alloc((size_t)Et * 4);
    int* csr      = (int*)alloc((size_t)Et * 4);
    (void)n_in; (void)out_size; (void)ws_size;

    const int* srcs = edges;
    const int* dsts = edges + E;

    hipMemsetAsync(bcnt, 0, NBMAX * 4, stream);

    k_binA<<<(Et + 2047) / 2048, 256, 0, stream>>>(dsts, bcnt, E, Et, NB);
    k_binB<<<1, 256, 0, stream>>>(bcnt, bbase, bcur, rp, NB, N, Et);
    k_binC<<<(Et + CHUNK - 1) / CHUNK, 256, 0, stream>>>(srcs, dsts, bcur, binned, E, Et, NB);
    k_binD<<<NB, 256, 0, stream>>>(binned, bbase, bcur, rp, csr, N);

    k_gemm1<<<(N + 63) / 64, 256, 0, stream>>>(x, W1, av_s1, av_d1, h1, as1, ad1, N);
    int gAgg = (N + 3) / 4;
    k_agg<F_H, true, false><<<gAgg, 256, 0, stream>>>(rp, csr, as1, ad1,
                                                      (const uint4*)h1, b1, out1, N);
    k_gemm2<<<(N + 63) / 64, 256, 0, stream>>>(out1, W2, av_s2, av_d2, h1, as2, ad2, N);
    k_agg<F_O, false, true><<<gAgg, 256, 0, stream>>>(rp, csr, as2, ad2,
                                                      (const uint4*)h1, b2, out, N);
}